// Round 11
// baseline (214.534 us; speedup 1.0000x reference)
//
#include <hip/hip_runtime.h>
#include <hip/hip_bf16.h>

#define C_DIM 100000
#define NROW 512
#define DDIM 512
#define BNC 64
#define NPANEL 1563            // ceil(C_DIM/64)
#define NBLK (NPANEL * 2)      // 3126: panel x row-half

typedef __attribute__((ext_vector_type(4))) float f32x4;
typedef __attribute__((ext_vector_type(8))) short bf16x8;
typedef __attribute__((ext_vector_type(4))) float f32acc;

// ---------------- kernel 1: norm2[d] = sum_c W[d][c]^2 --------------------------
__global__ __launch_bounds__(256) void cf_knorm(const float* __restrict__ W,
                                                float* __restrict__ norm2) {
    const int d = blockIdx.x;
    const float* row = W + (size_t)d * C_DIM;
    float s = 0.f;
    for (int c4 = threadIdx.x; c4 < C_DIM / 4; c4 += 256) {
        f32x4 v = *(const f32x4*)(row + c4 * 4);
        s += v.x * v.x + v.y * v.y + v.z * v.z + v.w * v.w;
    }
    #pragma unroll
    for (int off = 32; off; off >>= 1) s += __shfl_down(s, off, 64);
    __shared__ float wsum[4];
    if ((threadIdx.x & 63) == 0) wsum[threadIdx.x >> 6] = s;
    __syncthreads();
    if (threadIdx.x == 0) norm2[d] = wsum[0] + wsum[1] + wsum[2] + wsum[3];
}

// ------- kernel 2: xs2 = bf16(x * rsqrt(norm2)) fragment-tiled ------------------
// xs2[((row>>4)*64 + k8)*128 + (row&15)*8 + e]  (row=0..511, col=k8*8+e)
__global__ __launch_bounds__(256) void cf_kxs2(const float* __restrict__ x,
                                               const float* __restrict__ norm2,
                                               __hip_bfloat16* __restrict__ xs2) {
    const int idx = blockIdx.x * 256 + threadIdx.x;
    const int row = idx >> 6;
    const int k8  = idx & 63;
    const float* xp = x + (size_t)row * DDIM + k8 * 8;
    f32x4 v0 = *(const f32x4*)(xp);
    f32x4 v1 = *(const f32x4*)(xp + 4);
    union { __hip_bfloat16 h[8]; bf16x8 v; } p;
    #pragma unroll
    for (int e = 0; e < 4; ++e) p.h[e]     = __float2bfloat16(v0[e] * rsqrtf(norm2[k8 * 8 + e]));
    #pragma unroll
    for (int e = 0; e < 4; ++e) p.h[4 + e] = __float2bfloat16(v1[e] * rsqrtf(norm2[k8 * 8 + 4 + e]));
    *(bf16x8*)(xs2 + ((size_t)((row >> 4) * 64 + k8) * 128 + (row & 15) * 8)) = p.v;
}

// ---------------- kernel 3: target logits, cos_m, final -------------------------
__global__ __launch_bounds__(64) void cf_ktgt(const float* __restrict__ x,
                                              const float* __restrict__ W,
                                              const float* __restrict__ norm2,
                                              const int* __restrict__ label,
                                              float* __restrict__ tl,
                                              float* __restrict__ cm,
                                              float* __restrict__ fl) {
    const int i = blockIdx.x;
    const int lane = threadIdx.x;
    const int lab = label[i];
    float s = 0.f;
    for (int d = lane; d < DDIM; d += 64)
        s += x[(size_t)i * DDIM + d] * rsqrtf(norm2[d]) * W[(size_t)d * C_DIM + lab];
    #pragma unroll
    for (int off = 32; off; off >>= 1) s += __shfl_down(s, off, 64);
    if (lane == 0) {
        float t = fminf(fmaxf(s, -1.f), 1.f);
        float sn = sqrtf(fmaxf(1.f - t * t, 0.f));
        float c = t * 0.8775825618903728f - sn * 0.479425538604203f; // cos(th+m)
        tl[i] = t;
        cm[i] = c;
        fl[i] = (t > -0.8775825618903728f) ? c : (t - 0.2397127693021015f);
    }
}

// ---------------- kernel 4: t = 0.01 * mean(target_logit) -----------------------
__global__ __launch_bounds__(512) void cf_kt(const float* __restrict__ tl,
                                             float* __restrict__ tout) {
    float s = tl[threadIdx.x];
    #pragma unroll
    for (int off = 32; off; off >>= 1) s += __shfl_down(s, off, 64);
    __shared__ float w[8];
    if ((threadIdx.x & 63) == 0) w[threadIdx.x >> 6] = s;
    __syncthreads();
    if (threadIdx.x == 0) {
        float tt = 0.f;
        #pragma unroll
        for (int j = 0; j < 8; ++j) tt += w[j];
        tout[0] = 0.01f * (tt / 512.0f);
    }
}

// ---------------- kernel 5: 4-blocks/CU GEMM + fused epilogue -------------------
// Block = 256 thr (4 waves) x (row-half rh: 256 rows) x (64-col panel).
// LDS = one 32KB K-half, staged twice (register footprint identical to the
// 2-block champion -> 16 waves/CU = 4 independent blocks/CU whose stage/
// compute/write phases interleave via TLP). Twin row-blocks share an XCD
// (bijective chunk swizzle) so the duplicated panel fetch is L2-served.
__global__ __launch_bounds__(256, 4) void cf_kgemm8(
    const __hip_bfloat16* __restrict__ xs2,
    const float* __restrict__ W,
    const int* __restrict__ label,
    const float* __restrict__ cosm,
    const float* __restrict__ finl,
    const float* __restrict__ tp,
    float* __restrict__ out) {
    __shared__ __attribute__((aligned(16))) __hip_bfloat16 Bl[64 * 256];   // 32KB

    const int tid  = threadIdx.x;
    const int wv   = tid >> 6;       // 0..3
    const int lane = tid & 63;
    const int il   = lane & 15;
    const int hi   = lane >> 4;

    // bijective XCD chunk swizzle over 3126 blocks (3126 = 8*390 + 6)
    const int q8 = NBLK / 8, r8 = NBLK % 8;
    const int xcd = blockIdx.x % 8, pos = blockIdx.x / 8;
    const int sw  = (xcd < r8) ? xcd * (q8 + 1) + pos
                               : r8 * (q8 + 1) + (xcd - r8) * q8 + pos;
    const int pan = sw >> 1;         // panel (twin halves adjacent -> same XCD)
    const int rh  = sw & 1;          // row half: rows [rh*256, rh*256+256)
    const int cb  = pan * BNC;

    const int c4  = (tid & 15) * 4;  // col quad 0..60
    const int k16 = tid >> 4;        // 0..15 (16 k's per thread per half)
    const bool ok = (cb + c4) < C_DIM;   // C_DIM%4==0 -> quad all-or-nothing

    f32acc acc[4][4];
    #pragma unroll
    for (int m = 0; m < 4; ++m)
        #pragma unroll
        for (int n = 0; n < 4; ++n)
            acc[m][n] = (f32acc){0.f, 0.f, 0.f, 0.f};

    int crow[4];
    #pragma unroll
    for (int m = 0; m < 4; ++m) crow[m] = (m * 16 + il) * 256;

    auto loadB = [&](bf16x8 (&bb)[4], int ktA) {   // ktA = 0..15 panel-absolute
        #pragma unroll
        for (int n = 0; n < 4; ++n) {
            const int g = rh * 16 + wv * 4 + n;    // global 16-row group
            bb[n] = *(const bf16x8*)(xs2 + (size_t)(g * 64 + ktA * 4 + hi) * 128 + il * 8);
        }
    };
    auto step = [&](const bf16x8 (&bb)[4], int l) {   // l = 0..7 within half
        bf16x8 a[4];
        #pragma unroll
        for (int m = 0; m < 4; ++m) {
            const int c = m * 16 + il;
            const int q = (l * 4 + hi) ^ (c & 7);
            a[m] = *(const bf16x8*)&Bl[crow[m] + q * 8];
        }
        #pragma unroll
        for (int m = 0; m < 4; ++m)
            #pragma unroll
            for (int n = 0; n < 4; ++n)
                acc[m][n] = __builtin_amdgcn_mfma_f32_16x16x32_bf16(a[m], bb[n], acc[m][n], 0, 0, 0);
    };

    #pragma unroll
    for (int h = 0; h < 2; ++h) {
        if (h) __syncthreads();      // compute(h-1) done reading LDS
        // stage K-half h: per thread 4 cols x 16 k (two octets, v[8] reused)
        #pragma unroll
        for (int o = 0; o < 2; ++o) {
            const int kb = h * 256 + k16 * 16 + o * 8;
            f32x4 v[8];
            #pragma unroll
            for (int j = 0; j < 8; ++j) {
                if (ok) v[j] = *(const f32x4*)(W + (size_t)(kb + j) * C_DIM + cb + c4);
                else    v[j] = (f32x4){0.f, 0.f, 0.f, 0.f};
            }
            const int qq = k16 * 2 + o;   // 0..31
            #pragma unroll
            for (int cc = 0; cc < 4; ++cc) {
                const int c = c4 + cc;
                union { __hip_bfloat16 hh[8]; bf16x8 b; } p;
                #pragma unroll
                for (int j = 0; j < 8; ++j) p.hh[j] = __float2bfloat16(v[j][cc]);
                *(bf16x8*)&Bl[c * 256 + (qq ^ (c & 7)) * 8] = p.b;
            }
        }
        __syncthreads();
        // compute 8 kt from this half, b-frag ping-pong (1-ahead from L2 xs2)
        bf16x8 b0[4], b1[4];
        loadB(b0, h * 8);
        #pragma unroll
        for (int l = 0; l < 8; l += 2) {
            if (l + 1 < 8) loadB(b1, h * 8 + l + 1);
            step(b0, l);
            if (l + 2 < 8) loadB(b0, h * 8 + l + 2);
            if (l + 1 < 8) step(b1, l + 1);
        }
    }

    // fused epilogue: D[c][i]; i = rh*256 + wv*64 + n*16 + il, plain stores
    const float t = tp[0];
    const int ib = rh * 256 + wv * 64;
    #pragma unroll
    for (int n = 0; n < 4; ++n) {
        const int i = ib + n * 16 + il;
        const float cmv = cosm[i];
        const float flv = finl[i];
        const int lab = label[i];
        float* orow = out + (size_t)i * C_DIM;
        #pragma unroll
        for (int m = 0; m < 4; ++m) {
            const int c0 = cb + m * 16 + hi * 4;
            if (c0 < C_DIM) {
                f32x4 v = acc[m][n];
                f32x4 o;
                #pragma unroll
                for (int r = 0; r < 4; ++r) {
                    float cz = fminf(fmaxf(v[r], -1.f), 1.f);
                    float ov = (cz > cmv) ? cz * (t + cz) : cz;
                    if (c0 + r == lab) ov = flv;
                    o[r] = ov * 64.0f;
                }
                *(f32x4*)(orow + c0) = o;
            }
        }
    }
}

extern "C" void kernel_launch(void* const* d_in, const int* in_sizes, int n_in,
                              void* d_out, int out_size, void* d_ws, size_t ws_size,
                              hipStream_t stream) {
    const float* x   = (const float*)d_in[0];
    const float* W   = (const float*)d_in[1];
    const int* label = (const int*)d_in[2];
    float* out = (float*)d_out;

    char* ws = (char*)d_ws;
    float* norm2 = (float*)ws;             // 512 f32 (sum of squares)
    float* tl  = norm2 + 512;
    float* cm  = tl + 512;
    float* fl  = cm + 512;
    float* tsc = fl + 512;
    __hip_bfloat16* xs2 = (__hip_bfloat16*)(ws + 16384);  // 512*512 bf16 = 512KB

    cf_knorm<<<DDIM, 256, 0, stream>>>(W, norm2);
    cf_kxs2<<<128, 256, 0, stream>>>(x, norm2, xs2);
    cf_ktgt<<<NROW, 64, 0, stream>>>(x, W, norm2, label, tl, cm, fl);
    cf_kt<<<1, 512, 0, stream>>>(tl, tsc);

    cf_kgemm8<<<NBLK, 256, 0, stream>>>(xs2, W, label, cm, fl, tsc, out);
}